// Round 4
// baseline (755.796 us; speedup 1.0000x reference)
//
#include <hip/hip_runtime.h>

#define T_SEQ 2048
#define DMODEL 2048
#define NH 16
#define NKV 4
#define HD 128
#define ISZ 5632
#define BATCH 2
#define QKS 2560  // fused q|k row stride

typedef unsigned short ushort_t;
typedef __attribute__((ext_vector_type(8))) short short8;
typedef __attribute__((ext_vector_type(4))) float f32x4;

__device__ __forceinline__ ushort_t f2bf(float f) {
  unsigned int u = __float_as_uint(f);
  unsigned int r = (u + 0x7FFFu + ((u >> 16) & 1u)) >> 16;
  return (ushort_t)r;
}
__device__ __forceinline__ float bf2f(ushort_t h) {
  return __uint_as_float(((unsigned int)h) << 16);
}

// ---------------- weight fp32 (K,N) -> bf16 transposed (N,K) ----------------
__global__ __launch_bounds__(256) void wconv_kernel(const float* __restrict__ W,
                                                    ushort_t* __restrict__ Wt,
                                                    int K, int N) {
  __shared__ float tile[32][33];
  const int n0 = blockIdx.x * 32, k0 = blockIdx.y * 32;
  const int t = threadIdx.x;
  const int r = t >> 3, c = (t & 7) * 4;
  float4 v = *(const float4*)(W + (size_t)(k0 + r) * N + n0 + c);
  tile[r][c + 0] = v.x; tile[r][c + 1] = v.y; tile[r][c + 2] = v.z; tile[r][c + 3] = v.w;
  __syncthreads();
  ushort4 o;
  o.x = f2bf(tile[c + 0][r]);
  o.y = f2bf(tile[c + 1][r]);
  o.z = f2bf(tile[c + 2][r]);
  o.w = f2bf(tile[c + 3][r]);
  *(ushort4*)(Wt + (size_t)(n0 + r) * K + k0 + c) = o;
}

__global__ __launch_bounds__(256) void catbias_kernel(const float* __restrict__ a,
                                                      const float* __restrict__ b,
                                                      float* __restrict__ o) {
  int i = blockIdx.x * 256 + threadIdx.x;
  if (i < QKS) o[i] = (i < 2048) ? a[i] : b[i - 2048];
}

// ---------------- RMSNorm (f32 in, bf16 out), D = 2048, block = 256 ----------------
__global__ __launch_bounds__(256) void rmsnorm_kernel(const float* __restrict__ x,
                                                      const float* __restrict__ w,
                                                      ushort_t* __restrict__ out) {
  const int row = blockIdx.x;
  const int t = threadIdx.x;
  const float* xr = x + (size_t)row * DMODEL;
  float4 v0 = *(const float4*)(xr + t * 4);
  float4 v1 = *(const float4*)(xr + 1024 + t * 4);
  float ss = v0.x * v0.x + v0.y * v0.y + v0.z * v0.z + v0.w * v0.w +
             v1.x * v1.x + v1.y * v1.y + v1.z * v1.z + v1.w * v1.w;
  #pragma unroll
  for (int m = 1; m < 64; m <<= 1) ss += __shfl_xor(ss, m);
  __shared__ float red[4];
  if ((t & 63) == 0) red[t >> 6] = ss;
  __syncthreads();
  float tot = red[0] + red[1] + red[2] + red[3];
  float rinv = rsqrtf(tot * (1.0f / DMODEL) + 1e-5f);
  float4 w0 = *(const float4*)(w + t * 4);
  float4 w1 = *(const float4*)(w + 1024 + t * 4);
  ushort4 o0, o1;
  o0.x = f2bf(v0.x * rinv * w0.x); o0.y = f2bf(v0.y * rinv * w0.y);
  o0.z = f2bf(v0.z * rinv * w0.z); o0.w = f2bf(v0.w * rinv * w0.w);
  o1.x = f2bf(v1.x * rinv * w1.x); o1.y = f2bf(v1.y * rinv * w1.y);
  o1.z = f2bf(v1.z * rinv * w1.z); o1.w = f2bf(v1.w * rinv * w1.w);
  *(ushort4*)(out + (size_t)row * DMODEL + t * 4) = o0;
  *(ushort4*)(out + (size_t)row * DMODEL + 1024 + t * 4) = o1;
}

// ---------------- RoPE in place on fused q|k buffer (B*T, 20 head-slots, 128) ----------------
__global__ __launch_bounds__(256) void rope_kernel(ushort_t* __restrict__ buf,
                                                   const float* __restrict__ cs,
                                                   const float* __restrict__ sn) {
  size_t idx = (size_t)blockIdx.x * 256 + threadIdx.x;
  int d = (int)(idx & 63);
  size_t rest = idx >> 6;
  int hh = (int)(rest % 20);
  size_t bt = rest / 20;
  int t = (int)(bt & (T_SEQ - 1));
  ushort_t* p = buf + bt * QKS + hh * HD + 2 * d;
  float x1 = bf2f(p[0]), x2 = bf2f(p[1]);
  float c = cs[t * 64 + d], s = sn[t * 64 + d];
  p[0] = f2bf(x1 * c - x2 * s);
  p[1] = f2bf(x1 * s + x2 * c);
}

// ---------------- SwiGLU in place: gu[:, :I] = silu(gu[:, :I]) * gu[:, I:] ----------------
__global__ __launch_bounds__(256) void swiglu_kernel(ushort_t* __restrict__ gu) {
  size_t i = (size_t)blockIdx.x * 256 + threadIdx.x;
  size_t m = i / (ISZ / 8);
  size_t j = (i % (ISZ / 8)) * 8;
  ushort_t* pg = gu + m * (2 * ISZ) + j;
  short8 gg = *(const short8*)pg;
  short8 uu = *(const short8*)(pg + ISZ);
  short8 oo;
  #pragma unroll
  for (int q = 0; q < 8; ++q) {
    float gv = bf2f((ushort_t)gg[q]);
    float uv = bf2f((ushort_t)uu[q]);
    float sl = gv / (1.f + __expf(-gv));
    oo[q] = (short)f2bf(sl * uv);
  }
  *(short8*)pg = oo;
}

// ================= 256x256 pipelined GEMM: 8 waves, BK=64, swizzled LDS ==================
// A (M,K) bf16 row-major stride lda; Bt (N,K) bf16 row-major; out bf16 = A@B + bias.
// Hoisted swizzled addresses; 1 stage-pair per phase; barrier between reads and MFMA.
__global__ __launch_bounds__(512, 2)
void gemm256_kernel(const ushort_t* __restrict__ A, int lda,
                    const ushort_t* __restrict__ Bt,
                    const float* __restrict__ bias, void* __restrict__ outp,
                    int M, int N, int K, int nbx) {
  __shared__ ushort_t lds[65536];  // 128 KiB = 2 bufs x (A 32K | B 32K)
  const int tid = threadIdx.x;
  const int wid = tid >> 6, lane = tid & 63;
  const int lq = lane & 15, g = lane >> 4;
  const int wm = wid >> 2, wn = wid & 3;
  // XCD-aware block swizzle (grid size % 8 == 0 for all our shapes)
  const int nb = gridDim.x;
  const int wg = (blockIdx.x & 7) * (nb >> 3) + (blockIdx.x >> 3);
  const int m0 = (wg / nbx) * 256, n0 = (wg % nbx) * 256;
  const int NT = K >> 6;  // even for all our K

  const char* ldsc = (const char*)lds;
  // per-lane swizzled fragment base offsets (byte): addr = base + P*65536 + imm
  const int c0 = ((g ^ (lq & 3)) << 4) | (((lq >> 2) & 1) << 6);
  const int vAk0 = wm * 16384 + lq * 128 + c0;
  const int vAk1 = wm * 16384 + lq * 128 + (c0 ^ 64);
  const int vBk0 = 32768 + wn * 8192 + lq * 128 + c0;
  const int vBk1 = 32768 + wn * 8192 + lq * 128 + (c0 ^ 64);

  // hoisted stage source pointers (swizzle baked in); advance 128 B per K-tile
  const char* sA[4];
  const char* sB[4];
  #pragma unroll
  for (int j = 0; j < 4; ++j) {
    int pb = (wid * 4 + j) * 1024 + lane * 16;
    int ob = pb ^ (((pb >> 7) & 7) << 4);
    int row = ob >> 7, colb = ob & 127;
    sA[j] = (const char*)A + (size_t)(m0 + row) * (lda * 2) + colb;
    sB[j] = (const char*)Bt + (size_t)(n0 + row) * (K * 2) + colb;
  }

#define STG(J, PD)                                                            \
  {                                                                           \
    __builtin_amdgcn_global_load_lds(                                         \
        (const __attribute__((address_space(1))) void*)sA[J],                 \
        (__attribute__((address_space(3))) void*)(lds + (PD)*32768 + (wid * 4 + (J)) * 512), 16, 0, 0); \
    __builtin_amdgcn_global_load_lds(                                         \
        (const __attribute__((address_space(1))) void*)sB[J],                 \
        (__attribute__((address_space(3))) void*)(lds + (PD)*32768 + 16384 + (wid * 4 + (J)) * 512), 16, 0, 0); \
  }

  f32x4 acc[8][4] = {};
  // prologue: stage tile 0 -> buf 0
  STG(0, 0) STG(1, 0) STG(2, 0) STG(3, 0)
  #pragma unroll
  for (int j = 0; j < 4; ++j) { sA[j] += 128; sB[j] += 128; }

#define TILEBODY(P, TCUR)                                                     \
  {                                                                           \
    asm volatile("s_waitcnt vmcnt(0)" ::: "memory");                          \
    __builtin_amdgcn_s_barrier();                                             \
    const int aK0 = vAk0 + (P)*65536, aK1 = vAk1 + (P)*65536;                 \
    const int bK0 = vBk0 + (P)*65536, bK1 = vBk1 + (P)*65536;                 \
    const bool st = (TCUR) + 1 < NT;                                          \
    short8 aA[4][2], bb0[2][2], bb1[2][2];                                    \
    /* ph0: A half0 (8) + B half0 (4); stage pair 0 */                        \
    _Pragma("unroll") for (int mi = 0; mi < 4; ++mi) {                        \
      aA[mi][0] = *(const short8*)(ldsc + aK0 + mi * 2048);                   \
      aA[mi][1] = *(const short8*)(ldsc + aK1 + mi * 2048);                   \
    }                                                                         \
    _Pragma("unroll") for (int nj = 0; nj < 2; ++nj) {                        \
      bb0[nj][0] = *(const short8*)(ldsc + bK0 + nj * 2048);                  \
      bb0[nj][1] = *(const short8*)(ldsc + bK1 + nj * 2048);                  \
    }                                                                         \
    if (st) STG(0, (P) ^ 1)                                                   \
    __builtin_amdgcn_s_barrier();                                             \
    __builtin_amdgcn_s_setprio(1);                                            \
    _Pragma("unroll") for (int mi = 0; mi < 4; ++mi)                          \
      _Pragma("unroll") for (int nj = 0; nj < 2; ++nj) {                      \
        acc[mi][nj] = __builtin_amdgcn_mfma_f32_16x16x32_bf16(aA[mi][0], bb0[nj][0], acc[mi][nj], 0, 0, 0); \
        acc[mi][nj] = __builtin_amdgcn_mfma_f32_16x16x32_bf16(aA[mi][1], bb0[nj][1], acc[mi][nj], 0, 0, 0); \
      }                                                                       \
    __builtin_amdgcn_s_setprio(0);                                            \
    /* ph1: B half1 (4); stage pair 1 */                                      \
    _Pragma("unroll") for (int nj = 0; nj < 2; ++nj) {                        \
      bb1[nj][0] = *(const short8*)(ldsc + bK0 + 4096 + nj * 2048);           \
      bb1[nj][1] = *(const short8*)(ldsc + bK1 + 4096 + nj * 2048);           \
    }                                                                         \
    if (st) STG(1, (P) ^ 1)                                                   \
    __builtin_amdgcn_s_barrier();                                             \
    __builtin_amdgcn_s_setprio(1);                                            \
    _Pragma("unroll") for (int mi = 0; mi < 4; ++mi)                          \
      _Pragma("unroll") for (int nj = 0; nj < 2; ++nj) {                      \
        acc[mi][2 + nj] = __builtin_amdgcn_mfma_f32_16x16x32_bf16(aA[mi][0], bb1[nj][0], acc[mi][2 + nj], 0, 0, 0); \
        acc[mi][2 + nj] = __builtin_amdgcn_mfma_f32_16x16x32_bf16(aA[mi][1], bb1[nj][1], acc[mi][2 + nj], 0, 0, 0); \
      }                                                                       \
    __builtin_amdgcn_s_setprio(0);                                            \
    /* ph2: A half1 (8); stage pair 2 */                                      \
    _Pragma("unroll") for (int mi = 0; mi < 4; ++mi) {                        \
      aA[mi][0] = *(const short8*)(ldsc + aK0 + 8192 + mi * 2048);            \
      aA[mi][1] = *(const short8*)(ldsc + aK1 + 8192 + mi * 2048);            \
    }                                                                         \
    if (st) STG(2, (P) ^ 1)                                                   \
    __builtin_amdgcn_s_barrier();                                             \
    __builtin_amdgcn_s_setprio(1);                                            \
    _Pragma("unroll") for (int mi = 0; mi < 4; ++mi)                          \
      _Pragma("unroll") for (int nj = 0; nj < 2; ++nj) {                      \
        acc[4 + mi][nj] = __builtin_amdgcn_mfma_f32_16x16x32_bf16(aA[mi][0], bb0[nj][0], acc[4 + mi][nj], 0, 0, 0); \
        acc[4 + mi][nj] = __builtin_amdgcn_mfma_f32_16x16x32_bf16(aA[mi][1], bb0[nj][1], acc[4 + mi][nj], 0, 0, 0); \
      }                                                                       \
    __builtin_amdgcn_s_setprio(0);                                            \
    /* ph3: stage pair 3; MFMA quad (1,1) */                                  \
    if (st) STG(3, (P) ^ 1)                                                   \
    __builtin_amdgcn_s_barrier();                                             \
    __builtin_amdgcn_s_setprio(1);                                            \
    _Pragma("unroll") for (int mi = 0; mi < 4; ++mi)                          \
      _Pragma("unroll") for (int nj = 0; nj < 2; ++nj) {                      \
        acc[4 + mi][2 + nj] = __builtin_amdgcn_mfma_f32_16x16x32_bf16(aA[mi][0], bb1[nj][0], acc[4 + mi][2 + nj], 0, 0, 0); \
        acc[4 + mi][2 + nj] = __builtin_amdgcn_mfma_f32_16x16x32_bf16(aA[mi][1], bb1[nj][1], acc[4 + mi][2 + nj], 0, 0, 0); \
      }                                                                       \
    __builtin_amdgcn_s_setprio(0);                                            \
    _Pragma("unroll") for (int j = 0; j < 4; ++j) { sA[j] += 128; sB[j] += 128; } \
  }

  for (int t = 0; t < NT; t += 2) {
    TILEBODY(0, t)
    TILEBODY(1, t + 1)
  }
#undef TILEBODY
#undef STG

  #pragma unroll
  for (int nf = 0; nf < 4; ++nf) {
    int c = n0 + wn * 64 + nf * 16 + lq;
    float bb = bias[c];
    #pragma unroll
    for (int mf = 0; mf < 8; ++mf) {
      #pragma unroll
      for (int i = 0; i < 4; ++i) {
        int r = m0 + wm * 128 + mf * 16 + g * 4 + i;
        ((ushort_t*)outp)[(size_t)r * N + c] = f2bf(acc[mf][nf][i] + bb);
      }
    }
  }
}

// ---------------- 128x128 GEMM (kept for Wo / W2 / V) ----------------
// MODE 1: out f32 = res + A@B + bias;  MODE 3: bf16 out written V^T per-kv-head
#define BM 128
#define BN 128
#define BK 32

template <int MODE>
__global__ __launch_bounds__(256, 2)
void gemm_kernel(const ushort_t* __restrict__ A, int lda, const ushort_t* __restrict__ Bt,
                 const float* __restrict__ bias, const float* __restrict__ res,
                 void* __restrict__ outp, int M, int N, int K) {
  __shared__ ushort_t Alds[BM * BK];
  __shared__ ushort_t Blds[BM * BK];
  const int tid = threadIdx.x;
  const int w = tid >> 6, lane = tid & 63;
  const int lq = lane & 15, g = lane >> 4;
  const int m0 = blockIdx.y * BM, n0 = blockIdx.x * BN;
  const int ro = (w >> 1) * 64, co = (w & 1) * 64;

  f32x4 acc[4][4] = {};

  for (int k0 = 0; k0 < K; k0 += BK) {
    const ushort_t* ga = A + (size_t)m0 * lda + k0;
    const ushort_t* gb = Bt + (size_t)n0 * K + k0;
    #pragma unroll
    for (int it = 0; it < 2; ++it) {
      int ch = it * 256 + tid;
      int row = ch >> 2, cir = ch & 3;
      int lbase = (it * 256 + w * 64) * 8;
      __builtin_amdgcn_global_load_lds(
          (const __attribute__((address_space(1))) void*)(ga + (size_t)row * lda + cir * 8),
          (__attribute__((address_space(3))) void*)(&Alds[lbase]), 16, 0, 0);
      __builtin_amdgcn_global_load_lds(
          (const __attribute__((address_space(1))) void*)(gb + (size_t)row * K + cir * 8),
          (__attribute__((address_space(3))) void*)(&Blds[lbase]), 16, 0, 0);
    }
    __syncthreads();
    short8 af[4], br[4];
    #pragma unroll
    for (int mi = 0; mi < 4; ++mi)
      af[mi] = *(const short8*)(&Alds[(ro + mi * 16 + lq) * BK + g * 8]);
    #pragma unroll
    for (int ni = 0; ni < 4; ++ni)
      br[ni] = *(const short8*)(&Blds[(co + ni * 16 + lq) * BK + g * 8]);
    #pragma unroll
    for (int mi = 0; mi < 4; ++mi)
      #pragma unroll
      for (int ni = 0; ni < 4; ++ni)
        acc[mi][ni] = __builtin_amdgcn_mfma_f32_16x16x32_bf16(af[mi], br[ni], acc[mi][ni], 0, 0, 0);
    __syncthreads();
  }

  #pragma unroll
  for (int ni = 0; ni < 4; ++ni) {
    int c = n0 + co + ni * 16 + lq;
    float bb = bias[c];
    #pragma unroll
    for (int mi = 0; mi < 4; ++mi) {
      #pragma unroll
      for (int i = 0; i < 4; ++i) {
        int r = m0 + ro + mi * 16 + g * 4 + i;
        size_t oidx = (size_t)r * N + c;
        float av = acc[mi][ni][i] + bb;
        if (MODE == 1) {
          ((float*)outp)[oidx] = res[oidx] + av;
        } else {  // MODE 3
          int b2 = r >> 11, t2 = r & (T_SEQ - 1);
          int hk = c >> 7, dd = c & (HD - 1);
          ((ushort_t*)outp)[((size_t)(b2 * NKV + hk) * HD + dd) * T_SEQ + t2] = f2bf(av);
        }
      }
    }
  }
}

// ---------------- Flash attention, GQA causal, MFMA 16x16x32 ----------------
#define QB 64
#define KB 64
#define KSTR 136
#define VSTR 72
#define PSTR 72

__global__ __launch_bounds__(256, 2)
void attn_kernel(const ushort_t* __restrict__ qk, const ushort_t* __restrict__ vT,
                 ushort_t* __restrict__ ao) {
  __shared__ ushort_t Klds[KB * KSTR];
  __shared__ ushort_t Vlds[HD * VSTR];
  __shared__ ushort_t Plds[4][16 * PSTR];

  const int tid = threadIdx.x;
  const int w = tid >> 6, lane = tid & 63;
  const int lq = lane & 15, g = lane >> 4;
  const int nqb = T_SEQ / QB;
  const int xq = blockIdx.x;
  const int qi = (xq & 1) ? (nqb - 1 - (xq >> 1)) : (xq >> 1);
  const int qb = qi * QB;
  const int h = blockIdx.y;
  const int b = blockIdx.z;
  const int hkv = h >> 2;
  const int qw = qb + w * 16;
  const float scale = 0.08838834764831845f;

  short8 qf[4];
  {
    const ushort_t* qrow = qk + ((size_t)(b * T_SEQ + qw + lq) * QKS) + h * HD;
    #pragma unroll
    for (int ks = 0; ks < 4; ++ks) qf[ks] = *(const short8*)(qrow + ks * 32 + g * 8);
  }

  f32x4 of[8] = {};
  float m_run = -1e30f, l_run = 0.f;

  const ushort_t* kbase = qk + (size_t)b * T_SEQ * QKS + 2048 + hkv * HD;
  const ushort_t* vbase = vT + (size_t)(b * NKV + hkv) * HD * T_SEQ;

  const int nt = (qb + QB) / KB;
  for (int ti = 0; ti < nt; ++ti) {
    const int kt = ti * KB;
    #pragma unroll
    for (int it = 0; it < 4; ++it) {
      int ch = it * 256 + tid;
      int krow = ch >> 4, kdk = (ch & 15) * 8;
      *(short8*)(&Klds[krow * KSTR + kdk]) =
          *(const short8*)(kbase + (size_t)(kt + krow) * QKS + kdk);
      int vd = ch >> 3, vj = (ch & 7) * 8;
      *(short8*)(&Vlds[vd * VSTR + vj]) =
          *(const short8*)(vbase + (size_t)vd * T_SEQ + kt + vj);
    }
    __syncthreads();
    if (kt <= qw + 15) {
      f32x4 s[4] = {};
      __builtin_amdgcn_s_setprio(1);
      #pragma unroll
      for (int c = 0; c < 4; ++c)
        #pragma unroll
        for (int ks = 0; ks < 4; ++ks) {
          short8 kf = *(const short8*)(&Klds[(c * 16 + lq) * KSTR + ks * 32 + g * 8]);
          s[c] = __builtin_amdgcn_mfma_f32_16x16x32_bf16(kf, qf[ks], s[c], 0, 0, 0);
        }
      __builtin_amdgcn_s_setprio(0);
      const int qg = qw + lq;
      float sv[16];
      #pragma unroll
      for (int c = 0; c < 4; ++c)
        #pragma unroll
        for (int i = 0; i < 4; ++i) {
          int kvg = kt + c * 16 + 4 * g + i;
          float xx = s[c][i] * scale;
          sv[c * 4 + i] = (kvg > qg) ? -1e30f : xx;
        }
      float tmax = sv[0];
      #pragma unroll
      for (int j = 1; j < 16; ++j) tmax = fmaxf(tmax, sv[j]);
      tmax = fmaxf(tmax, __shfl_xor(tmax, 16));
      tmax = fmaxf(tmax, __shfl_xor(tmax, 32));
      float mnew = fmaxf(m_run, tmax);
      float corr = __expf(m_run - mnew);
      float pv[16];
      float ps = 0.f;
      #pragma unroll
      for (int j = 0; j < 16; ++j) { pv[j] = __expf(sv[j] - mnew); ps += pv[j]; }
      ps += __shfl_xor(ps, 16);
      ps += __shfl_xor(ps, 32);
      l_run = l_run * corr + ps;
      m_run = mnew;
      float c4[4];
      #pragma unroll
      for (int i = 0; i < 4; ++i) c4[i] = __shfl(corr, 4 * g + i);
      #pragma unroll
      for (int n = 0; n < 8; ++n)
        #pragma unroll
        for (int i = 0; i < 4; ++i) of[n][i] *= c4[i];
      #pragma unroll
      for (int c = 0; c < 4; ++c) {
        ushort4 pw;
        pw.x = f2bf(pv[c * 4 + 0]); pw.y = f2bf(pv[c * 4 + 1]);
        pw.z = f2bf(pv[c * 4 + 2]); pw.w = f2bf(pv[c * 4 + 3]);
        *(ushort4*)(&Plds[w][lq * PSTR + c * 16 + 4 * g]) = pw;
      }
      short8 pf0 = *(const short8*)(&Plds[w][lq * PSTR + g * 8]);
      short8 pf1 = *(const short8*)(&Plds[w][lq * PSTR + 32 + g * 8]);
      __builtin_amdgcn_s_setprio(1);
      #pragma unroll
      for (int n = 0; n < 8; ++n) {
        short8 vf0 = *(const short8*)(&Vlds[(n * 16 + lq) * VSTR + g * 8]);
        short8 vf1 = *(const short8*)(&Vlds[(n * 16 + lq) * VSTR + 32 + g * 8]);
        of[n] = __builtin_amdgcn_mfma_f32_16x16x32_bf16(pf0, vf0, of[n], 0, 0, 0);
        of[n] = __builtin_amdgcn_mfma_f32_16x16x32_bf16(pf1, vf1, of[n], 0, 0, 0);
      }
      __builtin_amdgcn_s_setprio(0);
    }
    __syncthreads();
  }
  float li[4];
  #pragma unroll
  for (int i = 0; i < 4; ++i) li[i] = 1.f / __shfl(l_run, 4 * g + i);
  #pragma unroll
  for (int n = 0; n < 8; ++n)
    #pragma unroll
    for (int i = 0; i < 4; ++i) {
      int tok = qw + 4 * g + i;
      ao[((size_t)(b * T_SEQ + tok) * (NH * HD)) + h * HD + n * 16 + lq] = f2bf(of[n][i] * li[i]);
    }
}

// ---------------- host ----------------
extern "C" void kernel_launch(void* const* d_in, const int* in_sizes, int n_in,
                              void* d_out, int out_size, void* d_ws, size_t ws_size,
                              hipStream_t stream) {
  const float* x   = (const float*)d_in[0];
  const float* rc  = (const float*)d_in[1];
  const float* rs  = (const float*)d_in[2];
  const float* ln1 = (const float*)d_in[3];
  const float* ln2 = (const float*)d_in[4];
  const float* wq  = (const float*)d_in[5];
  const float* wqb = (const float*)d_in[6];
  const float* wk  = (const float*)d_in[7];
  const float* wkb = (const float*)d_in[8];
  const float* wv  = (const float*)d_in[9];
  const float* wvb = (const float*)d_in[10];
  const float* wo  = (const float*)d_in[11];
  const float* wob = (const float*)d_in[12];
  const float* w1  = (const float*)d_in[13];
  const float* w1b = (const float*)d_in[14];
  const float* w2  = (const float*)d_in[15];
  const float* w2b = (const float*)d_in[16];

  char* ws = (char*)d_ws;
  size_t off = 0;
  auto alloc = [&](size_t bytes) {
    char* p = ws + off;
    off += (bytes + 255) & ~(size_t)255;
    return (void*)p;
  };
  const int M = BATCH * T_SEQ;  // 4096
  ushort_t* w1T  = (ushort_t*)alloc((size_t)11264 * 2048 * 2);
  ushort_t* w2T  = (ushort_t*)alloc((size_t)2048 * 5632 * 2);
  ushort_t* hbuf = (ushort_t*)alloc((size_t)M * 2048 * 2);    // h -> ao -> g
  ushort_t* vbufT= (ushort_t*)alloc((size_t)M * 512 * 2);     // V^T (b,hkv,d,t)
  float*    qkb  = (float*)alloc((size_t)QKS * 4);
  // --- overlay region: [wqkT | wvT | woT | qkbuf | extra] reused as gu after attention ---
  size_t guStart = off;
  ushort_t* wqkT = (ushort_t*)alloc((size_t)QKS * 2048 * 2);
  ushort_t* wvT  = (ushort_t*)alloc((size_t)512 * 2048 * 2);
  ushort_t* woT  = (ushort_t*)alloc((size_t)2048 * 2048 * 2);
  ushort_t* qkbuf= (ushort_t*)alloc((size_t)M * QKS * 2);
  size_t guBytes = (size_t)M * 11264 * 2;
  size_t used = off - guStart;
  if (guBytes > used) alloc(guBytes - used);
  ushort_t* gu = (ushort_t*)(ws + guStart);
  float* h1 = (float*)d_out;  // residual stream lives in d_out
  if (off > ws_size) return;

  // weight transpose-converts
  wconv_kernel<<<dim3(2048 / 32, 2048 / 32), 256, 0, stream>>>(wq, wqkT, 2048, 2048);
  wconv_kernel<<<dim3(512 / 32, 2048 / 32), 256, 0, stream>>>(wk, wqkT + (size_t)2048 * 2048, 2048, 512);
  wconv_kernel<<<dim3(512 / 32, 2048 / 32), 256, 0, stream>>>(wv, wvT, 2048, 512);
  wconv_kernel<<<dim3(2048 / 32, 2048 / 32), 256, 0, stream>>>(wo, woT, 2048, 2048);
  wconv_kernel<<<dim3(11264 / 32, 2048 / 32), 256, 0, stream>>>(w1, w1T, 2048, 11264);
  wconv_kernel<<<dim3(2048 / 32, 5632 / 32), 256, 0, stream>>>(w2, w2T, 5632, 2048);
  catbias_kernel<<<10, 256, 0, stream>>>(wqb, wkb, qkb);

  rmsnorm_kernel<<<M, 256, 0, stream>>>(x, ln1, hbuf);

  // fused Q|K projection (N=2560, grid 160) ; V on 128^2 with transposed write
  gemm256_kernel<<<dim3((QKS / 256) * (M / 256)), 512, 0, stream>>>(hbuf, 2048, wqkT, qkb, qkbuf, M, QKS, 2048, QKS / 256);
  gemm_kernel<3><<<dim3(512 / BN, M / BM), 256, 0, stream>>>(hbuf, 2048, wvT, wvb, nullptr, vbufT, M, 512, 2048);

  rope_kernel<<<(M * 20 * 64) / 256, 256, 0, stream>>>(qkbuf, rc, rs);

  attn_kernel<<<dim3(T_SEQ / QB, NH, BATCH), 256, 0, stream>>>(qkbuf, vbufT, hbuf);

  gemm_kernel<1><<<dim3(2048 / BN, M / BM), 256, 0, stream>>>(hbuf, 2048, woT, wob, x, h1, M, 2048, 2048);

  rmsnorm_kernel<<<M, 256, 0, stream>>>(h1, ln2, hbuf);  // g

  gemm256_kernel<<<dim3((11264 / 256) * (M / 256)), 512, 0, stream>>>(hbuf, 2048, w1T, w1b, gu, M, 11264, 2048, 11264 / 256);

  swiglu_kernel<<<(M * (ISZ / 8)) / 256, 256, 0, stream>>>(gu);

  gemm_kernel<1><<<dim3(2048 / BN, M / BM), 256, 0, stream>>>(gu, 11264, w2T, w2b, h1, (float*)d_out, M, 2048, 5632);

  (void)in_sizes; (void)n_in; (void)out_size;
}

// Round 5
// 728.108 us; speedup vs baseline: 1.0380x; 1.0380x over previous
//
#include <hip/hip_runtime.h>

#define T_SEQ 2048
#define DMODEL 2048
#define NH 16
#define NKV 4
#define HD 128
#define ISZ 5632
#define BATCH 2
#define QKS 2560  // fused q|k row stride

typedef unsigned short ushort_t;
typedef __attribute__((ext_vector_type(8))) short short8;
typedef __attribute__((ext_vector_type(4))) float f32x4;

__device__ __forceinline__ ushort_t f2bf(float f) {
  unsigned int u = __float_as_uint(f);
  unsigned int r = (u + 0x7FFFu + ((u >> 16) & 1u)) >> 16;
  return (ushort_t)r;
}
__device__ __forceinline__ float bf2f(ushort_t h) {
  return __uint_as_float(((unsigned int)h) << 16);
}

// ---------------- weight fp32 (K,N) -> bf16 transposed (N,K) ----------------
__global__ __launch_bounds__(256) void wconv_kernel(const float* __restrict__ W,
                                                    ushort_t* __restrict__ Wt,
                                                    int K, int N) {
  __shared__ float tile[32][33];
  const int n0 = blockIdx.x * 32, k0 = blockIdx.y * 32;
  const int t = threadIdx.x;
  const int r = t >> 3, c = (t & 7) * 4;
  float4 v = *(const float4*)(W + (size_t)(k0 + r) * N + n0 + c);
  tile[r][c + 0] = v.x; tile[r][c + 1] = v.y; tile[r][c + 2] = v.z; tile[r][c + 3] = v.w;
  __syncthreads();
  ushort4 o;
  o.x = f2bf(tile[c + 0][r]);
  o.y = f2bf(tile[c + 1][r]);
  o.z = f2bf(tile[c + 2][r]);
  o.w = f2bf(tile[c + 3][r]);
  *(ushort4*)(Wt + (size_t)(n0 + r) * K + k0 + c) = o;
}

__global__ __launch_bounds__(256) void catbias_kernel(const float* __restrict__ a,
                                                      const float* __restrict__ b,
                                                      float* __restrict__ o) {
  int i = blockIdx.x * 256 + threadIdx.x;
  if (i < QKS) o[i] = (i < 2048) ? a[i] : b[i - 2048];
}

// ---------------- RMSNorm (f32 in, bf16 out), D = 2048, block = 256 ----------------
__global__ __launch_bounds__(256) void rmsnorm_kernel(const float* __restrict__ x,
                                                      const float* __restrict__ w,
                                                      ushort_t* __restrict__ out) {
  const int row = blockIdx.x;
  const int t = threadIdx.x;
  const float* xr = x + (size_t)row * DMODEL;
  float4 v0 = *(const float4*)(xr + t * 4);
  float4 v1 = *(const float4*)(xr + 1024 + t * 4);
  float ss = v0.x * v0.x + v0.y * v0.y + v0.z * v0.z + v0.w * v0.w +
             v1.x * v1.x + v1.y * v1.y + v1.z * v1.z + v1.w * v1.w;
  #pragma unroll
  for (int m = 1; m < 64; m <<= 1) ss += __shfl_xor(ss, m);
  __shared__ float red[4];
  if ((t & 63) == 0) red[t >> 6] = ss;
  __syncthreads();
  float tot = red[0] + red[1] + red[2] + red[3];
  float rinv = rsqrtf(tot * (1.0f / DMODEL) + 1e-5f);
  float4 w0 = *(const float4*)(w + t * 4);
  float4 w1 = *(const float4*)(w + 1024 + t * 4);
  ushort4 o0, o1;
  o0.x = f2bf(v0.x * rinv * w0.x); o0.y = f2bf(v0.y * rinv * w0.y);
  o0.z = f2bf(v0.z * rinv * w0.z); o0.w = f2bf(v0.w * rinv * w0.w);
  o1.x = f2bf(v1.x * rinv * w1.x); o1.y = f2bf(v1.y * rinv * w1.y);
  o1.z = f2bf(v1.z * rinv * w1.z); o1.w = f2bf(v1.w * rinv * w1.w);
  *(ushort4*)(out + (size_t)row * DMODEL + t * 4) = o0;
  *(ushort4*)(out + (size_t)row * DMODEL + 1024 + t * 4) = o1;
}

// ---------------- RoPE in place on fused q|k buffer (B*T, 20 head-slots, 128) ----------------
__global__ __launch_bounds__(256) void rope_kernel(ushort_t* __restrict__ buf,
                                                   const float* __restrict__ cs,
                                                   const float* __restrict__ sn) {
  size_t idx = (size_t)blockIdx.x * 256 + threadIdx.x;
  int d = (int)(idx & 63);
  size_t rest = idx >> 6;
  int hh = (int)(rest % 20);
  size_t bt = rest / 20;
  int t = (int)(bt & (T_SEQ - 1));
  ushort_t* p = buf + bt * QKS + hh * HD + 2 * d;
  float x1 = bf2f(p[0]), x2 = bf2f(p[1]);
  float c = cs[t * 64 + d], s = sn[t * 64 + d];
  p[0] = f2bf(x1 * c - x2 * s);
  p[1] = f2bf(x1 * s + x2 * c);
}

// ---------------- SwiGLU in place: gu[:, :I] = silu(gu[:, :I]) * gu[:, I:] ----------------
__global__ __launch_bounds__(256) void swiglu_kernel(ushort_t* __restrict__ gu) {
  size_t i = (size_t)blockIdx.x * 256 + threadIdx.x;
  size_t m = i / (ISZ / 8);
  size_t j = (i % (ISZ / 8)) * 8;
  ushort_t* pg = gu + m * (2 * ISZ) + j;
  short8 gg = *(const short8*)pg;
  short8 uu = *(const short8*)(pg + ISZ);
  short8 oo;
  #pragma unroll
  for (int q = 0; q < 8; ++q) {
    float gv = bf2f((ushort_t)gg[q]);
    float uv = bf2f((ushort_t)uu[q]);
    float sl = gv / (1.f + __expf(-gv));
    oo[q] = (short)f2bf(sl * uv);
  }
  *(short8*)pg = oo;
}

// ================= 256x256 GEMM, counted-vmcnt half-tile pipeline =================
// A (M,K) bf16 stride lda; Bt (N,K) bf16; out bf16 = A@B + bias. K must be 2048 (NT=32).
// LDS per buf (64KB): A0[0,16K) rows{0-63,128-191} | A1[16K,32K) rows{64-127,192-255}
//                     B0[32K,48K) rows{wn*64+0..31} | B1[48K,64K) rows{wn*64+32..63}
// Stage order per tile: A0,B0,B1,A1 (one half per phase, 2 gll/wave each).
// Waits: ph0 vmcnt(4) [needs A0,B0], ph1 vmcnt(4) [B1], ph2 vmcnt(4) [A1]; last tile 4/2/0.
__global__ __launch_bounds__(512, 2)
void gemm256_kernel(const ushort_t* __restrict__ A, int lda,
                    const ushort_t* __restrict__ Bt,
                    const float* __restrict__ bias, void* __restrict__ outp,
                    int M, int N, int K) {
  __shared__ ushort_t lds[65536];  // 128 KiB = 2 bufs x 64KB
  const int tid = threadIdx.x;
  const int wid = tid >> 6, lane = tid & 63;
  const int lq = lane & 15, g = lane >> 4;
  const int wm = wid >> 2, wn = wid & 3;
  const int m0 = blockIdx.y * 256, n0 = blockIdx.x * 256;

  const char* ldsc = (const char*)lds;
  // read bases (bytes): swizzled col c0; k-half toggled by ^64
  const int c0 = ((g ^ (lq & 3)) << 4) | (((lq >> 2) & 1) << 6);
  const int rbA = wm * 8192 + lq * 128 + c0;
  const int rbAx = rbA ^ 64;
  const int rbB = 32768 + wn * 4096 + lq * 128 + c0;
  const int rbBx = rbB ^ 64;

  // stage source pointers (pre-swizzled); instruction i of wave covers slots wid*16+i*8+(lane>>3)
  const int l3 = lane >> 3;
  const int clog = ((lane & 7) ^ l3) << 4;
  const int s0 = wid * 16 + l3, s1 = s0 + 8;
  const int rA0 = (s0 & 63) + ((s0 >> 6) << 7);
  const int rA0b = (s1 & 63) + ((s1 >> 6) << 7);
  const int rB0 = ((s0 >> 5) << 6) + (s0 & 31);
  const int rB0b = ((s1 >> 5) << 6) + (s1 & 31);
  const char* pA0a = (const char*)A + (size_t)(m0 + rA0) * (lda * 2) + clog;
  const char* pA0b = (const char*)A + (size_t)(m0 + rA0b) * (lda * 2) + clog;
  const char* pA1a = pA0a + (size_t)64 * (lda * 2);
  const char* pA1b = pA0b + (size_t)64 * (lda * 2);
  const char* pB0a = (const char*)Bt + (size_t)(n0 + rB0) * (K * 2) + clog;
  const char* pB0b = (const char*)Bt + (size_t)(n0 + rB0b) * (K * 2) + clog;
  const char* pB1a = pB0a + (size_t)32 * (K * 2);
  const char* pB1b = pB0b + (size_t)32 * (K * 2);
  ushort_t* sd = lds + wid * 1024;  // + PB*32768 + half*8192 + i*512 (ushort units)

#define GLL(SRC, DOFF)                                                        \
  __builtin_amdgcn_global_load_lds(                                           \
      (const __attribute__((address_space(1))) void*)(SRC),                   \
      (__attribute__((address_space(3))) void*)(sd + (DOFF)), 16, 0, 0)
#define STG_A0(PB) { GLL(pA0a, (PB)*32768 + 0);     GLL(pA0b, (PB)*32768 + 512); }
#define STG_A1(PB) { GLL(pA1a, (PB)*32768 + 8192);  GLL(pA1b, (PB)*32768 + 8704); }
#define STG_B0(PB) { GLL(pB0a, (PB)*32768 + 16384); GLL(pB0b, (PB)*32768 + 16896); }
#define STG_B1(PB) { GLL(pB1a, (PB)*32768 + 24576); GLL(pB1b, (PB)*32768 + 25088); }
#define ADV { pA0a += 128; pA0b += 128; pA1a += 128; pA1b += 128;             \
              pB0a += 128; pB0b += 128; pB1a += 128; pB1b += 128; }
#define PH_WAIT(NN) asm volatile("s_waitcnt vmcnt(" #NN ")" ::: "memory")
#define FENCE asm volatile("" ::: "memory")

  f32x4 acc[8][4] = {};

#define TILE(P, DOST, V0, V1, V2)                                             \
  {                                                                           \
    short8 aA[4][2], bb0[2][2], bb1[2][2];                                    \
    /* ---- phase 0: quad(0,0) ---- */                                        \
    PH_WAIT(V0);                                                              \
    __builtin_amdgcn_s_barrier();                                             \
    FENCE;                                                                    \
    _Pragma("unroll") for (int mi = 0; mi < 4; ++mi) {                        \
      aA[mi][0] = *(const short8*)(ldsc + (P)*65536 + rbA + mi * 2048);       \
      aA[mi][1] = *(const short8*)(ldsc + (P)*65536 + rbAx + mi * 2048);      \
    }                                                                         \
    _Pragma("unroll") for (int nj = 0; nj < 2; ++nj) {                        \
      bb0[nj][0] = *(const short8*)(ldsc + (P)*65536 + rbB + nj * 2048);      \
      bb0[nj][1] = *(const short8*)(ldsc + (P)*65536 + rbBx + nj * 2048);     \
    }                                                                         \
    if (DOST) STG_A0((P) ^ 1);                                                \
    __builtin_amdgcn_s_setprio(1);                                            \
    _Pragma("unroll") for (int mi = 0; mi < 4; ++mi)                          \
      _Pragma("unroll") for (int nj = 0; nj < 2; ++nj) {                      \
        acc[mi][nj] = __builtin_amdgcn_mfma_f32_16x16x32_bf16(aA[mi][0], bb0[nj][0], acc[mi][nj], 0, 0, 0); \
        acc[mi][nj] = __builtin_amdgcn_mfma_f32_16x16x32_bf16(aA[mi][1], bb0[nj][1], acc[mi][nj], 0, 0, 0); \
      }                                                                       \
    __builtin_amdgcn_s_setprio(0);                                            \
    /* ---- phase 1: quad(0,1) ---- */                                        \
    PH_WAIT(V1);                                                              \
    __builtin_amdgcn_s_barrier();                                             \
    FENCE;                                                                    \
    _Pragma("unroll") for (int nj = 0; nj < 2; ++nj) {                        \
      bb1[nj][0] = *(const short8*)(ldsc + (P)*65536 + rbB + 16384 + nj * 2048);  \
      bb1[nj][1] = *(const short8*)(ldsc + (P)*65536 + rbBx + 16384 + nj * 2048); \
    }                                                                         \
    if (DOST) STG_B0((P) ^ 1);                                                \
    __builtin_amdgcn_s_setprio(1);                                            \
    _Pragma("unroll") for (int mi = 0; mi < 4; ++mi)                          \
      _Pragma("unroll") for (int nj = 0; nj < 2; ++nj) {                      \
        acc[mi][2 + nj] = __builtin_amdgcn_mfma_f32_16x16x32_bf16(aA[mi][0], bb1[nj][0], acc[mi][2 + nj], 0, 0, 0); \
        acc[mi][2 + nj] = __builtin_amdgcn_mfma_f32_16x16x32_bf16(aA[mi][1], bb1[nj][1], acc[mi][2 + nj], 0, 0, 0); \
      }                                                                       \
    __builtin_amdgcn_s_setprio(0);                                            \
    /* ---- phase 2: quad(1,0) ---- */                                        \
    PH_WAIT(V2);                                                              \
    __builtin_amdgcn_s_barrier();                                             \
    FENCE;                                                                    \
    _Pragma("unroll") for (int mi = 0; mi < 4; ++mi) {                        \
      aA[mi][0] = *(const short8*)(ldsc + (P)*65536 + rbA + 16384 + mi * 2048);   \
      aA[mi][1] = *(const short8*)(ldsc + (P)*65536 + rbAx + 16384 + mi * 2048);  \
    }                                                                         \
    if (DOST) STG_B1((P) ^ 1);                                                \
    __builtin_amdgcn_s_setprio(1);                                            \
    _Pragma("unroll") for (int mi = 0; mi < 4; ++mi)                          \
      _Pragma("unroll") for (int nj = 0; nj < 2; ++nj) {                      \
        acc[4 + mi][nj] = __builtin_amdgcn_mfma_f32_16x16x32_bf16(aA[mi][0], bb0[nj][0], acc[4 + mi][nj], 0, 0, 0); \
        acc[4 + mi][nj] = __builtin_amdgcn_mfma_f32_16x16x32_bf16(aA[mi][1], bb0[nj][1], acc[4 + mi][nj], 0, 0, 0); \
      }                                                                       \
    __builtin_amdgcn_s_setprio(0);                                            \
    /* ---- phase 3: quad(1,1), no wait/barrier (pure reg) ---- */            \
    if (DOST) STG_A1((P) ^ 1);                                                \
    __builtin_amdgcn_s_setprio(1);                                            \
    _Pragma("unroll") for (int mi = 0; mi < 4; ++mi)                          \
      _Pragma("unroll") for (int nj = 0; nj < 2; ++nj) {                      \
        acc[4 + mi][2 + nj] = __builtin_amdgcn_mfma_f32_16x16x32_bf16(aA[mi][0], bb1[nj][0], acc[4 + mi][2 + nj], 0, 0, 0); \
        acc[4 + mi][2 + nj] = __builtin_amdgcn_mfma_f32_16x16x32_bf16(aA[mi][1], bb1[nj][1], acc[4 + mi][2 + nj], 0, 0, 0); \
      }                                                                       \
    __builtin_amdgcn_s_setprio(0);                                            \
    if (DOST) ADV;                                                            \
  }

  // prologue: stage tile 0 into buf 0 (order A0,B0,B1,A1), advance to tile 1
  STG_A0(0) STG_B0(0) STG_B1(0) STG_A1(0)
  ADV;
  // NT = 32: 15 pairs + tile30(stage) + tile31(drain)
  for (int it = 0; it < 15; ++it) {
    TILE(0, true, 4, 4, 4)
    TILE(1, true, 4, 4, 4)
  }
  TILE(0, true, 4, 4, 4)
  TILE(1, false, 4, 2, 0)
#undef TILE
#undef GLL
#undef STG_A0
#undef STG_A1
#undef STG_B0
#undef STG_B1
#undef ADV
#undef PH_WAIT
#undef FENCE

  #pragma unroll
  for (int nf = 0; nf < 4; ++nf) {
    int c = n0 + wn * 64 + nf * 16 + lq;
    float bb = bias[c];
    #pragma unroll
    for (int mf = 0; mf < 8; ++mf) {
      #pragma unroll
      for (int i = 0; i < 4; ++i) {
        int r = m0 + wm * 128 + mf * 16 + g * 4 + i;
        ((ushort_t*)outp)[(size_t)r * N + c] = f2bf(acc[mf][nf][i] + bb);
      }
    }
  }
}

// ---------------- 128x128 GEMM (kept for Wo / W2 / V) ----------------
// MODE 1: out f32 = res + A@B + bias;  MODE 3: bf16 out written V^T per-kv-head
#define BM 128
#define BN 128
#define BK 32

template <int MODE>
__global__ __launch_bounds__(256, 2)
void gemm_kernel(const ushort_t* __restrict__ A, int lda, const ushort_t* __restrict__ Bt,
                 const float* __restrict__ bias, const float* __restrict__ res,
                 void* __restrict__ outp, int M, int N, int K) {
  __shared__ ushort_t Alds[BM * BK];
  __shared__ ushort_t Blds[BM * BK];
  const int tid = threadIdx.x;
  const int w = tid >> 6, lane = tid & 63;
  const int lq = lane & 15, g = lane >> 4;
  const int m0 = blockIdx.y * BM, n0 = blockIdx.x * BN;
  const int ro = (w >> 1) * 64, co = (w & 1) * 64;

  f32x4 acc[4][4] = {};

  for (int k0 = 0; k0 < K; k0 += BK) {
    const ushort_t* ga = A + (size_t)m0 * lda + k0;
    const ushort_t* gb = Bt + (size_t)n0 * K + k0;
    #pragma unroll
    for (int it = 0; it < 2; ++it) {
      int ch = it * 256 + tid;
      int row = ch >> 2, cir = ch & 3;
      int lbase = (it * 256 + w * 64) * 8;
      __builtin_amdgcn_global_load_lds(
          (const __attribute__((address_space(1))) void*)(ga + (size_t)row * lda + cir * 8),
          (__attribute__((address_space(3))) void*)(&Alds[lbase]), 16, 0, 0);
      __builtin_amdgcn_global_load_lds(
          (const __attribute__((address_space(1))) void*)(gb + (size_t)row * K + cir * 8),
          (__attribute__((address_space(3))) void*)(&Blds[lbase]), 16, 0, 0);
    }
    __syncthreads();
    short8 af[4], br[4];
    #pragma unroll
    for (int mi = 0; mi < 4; ++mi)
      af[mi] = *(const short8*)(&Alds[(ro + mi * 16 + lq) * BK + g * 8]);
    #pragma unroll
    for (int ni = 0; ni < 4; ++ni)
      br[ni] = *(const short8*)(&Blds[(co + ni * 16 + lq) * BK + g * 8]);
    #pragma unroll
    for (int mi = 0; mi < 4; ++mi)
      #pragma unroll
      for (int ni = 0; ni < 4; ++ni)
        acc[mi][ni] = __builtin_amdgcn_mfma_f32_16x16x32_bf16(af[mi], br[ni], acc[mi][ni], 0, 0, 0);
    __syncthreads();
  }

  #pragma unroll
  for (int ni = 0; ni < 4; ++ni) {
    int c = n0 + co + ni * 16 + lq;
    float bb = bias[c];
    #pragma unroll
    for (int mi = 0; mi < 4; ++mi) {
      #pragma unroll
      for (int i = 0; i < 4; ++i) {
        int r = m0 + ro + mi * 16 + g * 4 + i;
        size_t oidx = (size_t)r * N + c;
        float av = acc[mi][ni][i] + bb;
        if (MODE == 1) {
          ((float*)outp)[oidx] = res[oidx] + av;
        } else {  // MODE 3
          int b2 = r >> 11, t2 = r & (T_SEQ - 1);
          int hk = c >> 7, dd = c & (HD - 1);
          ((ushort_t*)outp)[((size_t)(b2 * NKV + hk) * HD + dd) * T_SEQ + t2] = f2bf(av);
        }
      }
    }
  }
}

// ---------------- Flash attention, GQA causal, MFMA 16x16x32 ----------------
#define QB 64
#define KB 64
#define KSTR 136
#define VSTR 72
#define PSTR 72

__global__ __launch_bounds__(256, 2)
void attn_kernel(const ushort_t* __restrict__ qk, const ushort_t* __restrict__ vT,
                 ushort_t* __restrict__ ao) {
  __shared__ ushort_t Klds[KB * KSTR];
  __shared__ ushort_t Vlds[HD * VSTR];
  __shared__ ushort_t Plds[4][16 * PSTR];

  const int tid = threadIdx.x;
  const int w = tid >> 6, lane = tid & 63;
  const int lq = lane & 15, g = lane >> 4;
  const int nqb = T_SEQ / QB;
  const int xq = blockIdx.x;
  const int qi = (xq & 1) ? (nqb - 1 - (xq >> 1)) : (xq >> 1);
  const int qb = qi * QB;
  const int h = blockIdx.y;
  const int b = blockIdx.z;
  const int hkv = h >> 2;
  const int qw = qb + w * 16;
  const float scale = 0.08838834764831845f;

  short8 qf[4];
  {
    const ushort_t* qrow = qk + ((size_t)(b * T_SEQ + qw + lq) * QKS) + h * HD;
    #pragma unroll
    for (int ks = 0; ks < 4; ++ks) qf[ks] = *(const short8*)(qrow + ks * 32 + g * 8);
  }

  f32x4 of[8] = {};
  float m_run = -1e30f, l_run = 0.f;

  const ushort_t* kbase = qk + (size_t)b * T_SEQ * QKS + 2048 + hkv * HD;
  const ushort_t* vbase = vT + (size_t)(b * NKV + hkv) * HD * T_SEQ;

  const int nt = (qb + QB) / KB;
  for (int ti = 0; ti < nt; ++ti) {
    const int kt = ti * KB;
    #pragma unroll
    for (int it = 0; it < 4; ++it) {
      int ch = it * 256 + tid;
      int krow = ch >> 4, kdk = (ch & 15) * 8;
      *(short8*)(&Klds[krow * KSTR + kdk]) =
          *(const short8*)(kbase + (size_t)(kt + krow) * QKS + kdk);
      int vd = ch >> 3, vj = (ch & 7) * 8;
      *(short8*)(&Vlds[vd * VSTR + vj]) =
          *(const short8*)(vbase + (size_t)vd * T_SEQ + kt + vj);
    }
    __syncthreads();
    if (kt <= qw + 15) {
      f32x4 s[4] = {};
      __builtin_amdgcn_s_setprio(1);
      #pragma unroll
      for (int c = 0; c < 4; ++c)
        #pragma unroll
        for (int ks = 0; ks < 4; ++ks) {
          short8 kf = *(const short8*)(&Klds[(c * 16 + lq) * KSTR + ks * 32 + g * 8]);
          s[c] = __builtin_amdgcn_mfma_f32_16x16x32_bf16(kf, qf[ks], s[c], 0, 0, 0);
        }
      __builtin_amdgcn_s_setprio(0);
      const int qg = qw + lq;
      float sv[16];
      #pragma unroll
      for (int c = 0; c < 4; ++c)
        #pragma unroll
        for (int i = 0; i < 4; ++i) {
          int kvg = kt + c * 16 + 4 * g + i;
          float xx = s[c][i] * scale;
          sv[c * 4 + i] = (kvg > qg) ? -1e30f : xx;
        }
      float tmax = sv[0];
      #pragma unroll
      for (int j = 1; j < 16; ++j) tmax = fmaxf(tmax, sv[j]);
      tmax = fmaxf(tmax, __shfl_xor(tmax, 16));
      tmax = fmaxf(tmax, __shfl_xor(tmax, 32));
      float mnew = fmaxf(m_run, tmax);
      float corr = __expf(m_run - mnew);
      float pv[16];
      float ps = 0.f;
      #pragma unroll
      for (int j = 0; j < 16; ++j) { pv[j] = __expf(sv[j] - mnew); ps += pv[j]; }
      ps += __shfl_xor(ps, 16);
      ps += __shfl_xor(ps, 32);
      l_run = l_run * corr + ps;
      m_run = mnew;
      float c4[4];
      #pragma unroll
      for (int i = 0; i < 4; ++i) c4[i] = __shfl(corr, 4 * g + i);
      #pragma unroll
      for (int n = 0; n < 8; ++n)
        #pragma unroll
        for (int i = 0; i < 4; ++i) of[n][i] *= c4[i];
      #pragma unroll
      for (int c = 0; c < 4; ++c) {
        ushort4 pw;
        pw.x = f2bf(pv[c * 4 + 0]); pw.y = f2bf(pv[c * 4 + 1]);
        pw.z = f2bf(pv[c * 4 + 2]); pw.w = f2bf(pv[c * 4 + 3]);
        *(ushort4*)(&Plds[w][lq * PSTR + c * 16 + 4 * g]) = pw;
      }
      short8 pf0 = *(const short8*)(&Plds[w][lq * PSTR + g * 8]);
      short8 pf1 = *(const short8*)(&Plds[w][lq * PSTR + 32 + g * 8]);
      __builtin_amdgcn_s_setprio(1);
      #pragma unroll
      for (int n = 0; n < 8; ++n) {
        short8 vf0 = *(const short8*)(&Vlds[(n * 16 + lq) * VSTR + g * 8]);
        short8 vf1 = *(const short8*)(&Vlds[(n * 16 + lq) * VSTR + 32 + g * 8]);
        of[n] = __builtin_amdgcn_mfma_f32_16x16x32_bf16(pf0, vf0, of[n], 0, 0, 0);
        of[n] = __builtin_amdgcn_mfma_f32_16x16x32_bf16(pf1, vf1, of[n], 0, 0, 0);
      }
      __builtin_amdgcn_s_setprio(0);
    }
    __syncthreads();
  }
  float li[4];
  #pragma unroll
  for (int i = 0; i < 4; ++i) li[i] = 1.f / __shfl(l_run, 4 * g + i);
  #pragma unroll
  for (int n = 0; n < 8; ++n)
    #pragma unroll
    for (int i = 0; i < 4; ++i) {
      int tok = qw + 4 * g + i;
      ao[((size_t)(b * T_SEQ + tok) * (NH * HD)) + h * HD + n * 16 + lq] = f2bf(of[n][i] * li[i]);
    }
}

// ---------------- host ----------------
extern "C" void kernel_launch(void* const* d_in, const int* in_sizes, int n_in,
                              void* d_out, int out_size, void* d_ws, size_t ws_size,
                              hipStream_t stream) {
  const float* x   = (const float*)d_in[0];
  const float* rc  = (const float*)d_in[1];
  const float* rs  = (const float*)d_in[2];
  const float* ln1 = (const float*)d_in[3];
  const float* ln2 = (const float*)d_in[4];
  const float* wq  = (const float*)d_in[5];
  const float* wqb = (const float*)d_in[6];
  const float* wk  = (const float*)d_in[7];
  const float* wkb = (const float*)d_in[8];
  const float* wv  = (const float*)d_in[9];
  const float* wvb = (const float*)d_in[10];
  const float* wo  = (const float*)d_in[11];
  const float* wob = (const float*)d_in[12];
  const float* w1  = (const float*)d_in[13];
  const float* w1b = (const float*)d_in[14];
  const float* w2  = (const float*)d_in[15];
  const float* w2b = (const float*)d_in[16];

  char* ws = (char*)d_ws;
  size_t off = 0;
  auto alloc = [&](size_t bytes) {
    char* p = ws + off;
    off += (bytes + 255) & ~(size_t)255;
    return (void*)p;
  };
  const int M = BATCH * T_SEQ;  // 4096
  ushort_t* w1T  = (ushort_t*)alloc((size_t)11264 * 2048 * 2);
  ushort_t* w2T  = (ushort_t*)alloc((size_t)2048 * 5632 * 2);
  ushort_t* hbuf = (ushort_t*)alloc((size_t)M * 2048 * 2);    // h -> ao -> g
  ushort_t* vbufT= (ushort_t*)alloc((size_t)M * 512 * 2);     // V^T (b,hkv,d,t)
  float*    qkb  = (float*)alloc((size_t)QKS * 4);
  // --- overlay region: [wqkT | wvT | woT | qkbuf | extra] reused as gu after attention ---
  size_t guStart = off;
  ushort_t* wqkT = (ushort_t*)alloc((size_t)QKS * 2048 * 2);
  ushort_t* wvT  = (ushort_t*)alloc((size_t)512 * 2048 * 2);
  ushort_t* woT  = (ushort_t*)alloc((size_t)2048 * 2048 * 2);
  ushort_t* qkbuf= (ushort_t*)alloc((size_t)M * QKS * 2);
  size_t guBytes = (size_t)M * 11264 * 2;
  size_t used = off - guStart;
  if (guBytes > used) alloc(guBytes - used);
  ushort_t* gu = (ushort_t*)(ws + guStart);
  float* h1 = (float*)d_out;  // residual stream lives in d_out
  if (off > ws_size) return;

  // weight transpose-converts
  wconv_kernel<<<dim3(2048 / 32, 2048 / 32), 256, 0, stream>>>(wq, wqkT, 2048, 2048);
  wconv_kernel<<<dim3(512 / 32, 2048 / 32), 256, 0, stream>>>(wk, wqkT + (size_t)2048 * 2048, 2048, 512);
  wconv_kernel<<<dim3(512 / 32, 2048 / 32), 256, 0, stream>>>(wv, wvT, 2048, 512);
  wconv_kernel<<<dim3(2048 / 32, 2048 / 32), 256, 0, stream>>>(wo, woT, 2048, 2048);
  wconv_kernel<<<dim3(11264 / 32, 2048 / 32), 256, 0, stream>>>(w1, w1T, 2048, 11264);
  wconv_kernel<<<dim3(2048 / 32, 5632 / 32), 256, 0, stream>>>(w2, w2T, 5632, 2048);
  catbias_kernel<<<10, 256, 0, stream>>>(wqb, wkb, qkb);

  rmsnorm_kernel<<<M, 256, 0, stream>>>(x, ln1, hbuf);

  // fused Q|K projection (N=2560); V on 128^2 with transposed write
  gemm256_kernel<<<dim3(QKS / 256, M / 256), 512, 0, stream>>>(hbuf, 2048, wqkT, qkb, qkbuf, M, QKS, 2048);
  gemm_kernel<3><<<dim3(512 / BN, M / BM), 256, 0, stream>>>(hbuf, 2048, wvT, wvb, nullptr, vbufT, M, 512, 2048);

  rope_kernel<<<(M * 20 * 64) / 256, 256, 0, stream>>>(qkbuf, rc, rs);

  attn_kernel<<<dim3(T_SEQ / QB, NH, BATCH), 256, 0, stream>>>(qkbuf, vbufT, hbuf);

  gemm_kernel<1><<<dim3(2048 / BN, M / BM), 256, 0, stream>>>(hbuf, 2048, woT, wob, x, h1, M, 2048, 2048);

  rmsnorm_kernel<<<M, 256, 0, stream>>>(h1, ln2, hbuf);  // g

  gemm256_kernel<<<dim3(11264 / 256, M / 256), 512, 0, stream>>>(hbuf, 2048, w1T, w1b, gu, M, 11264, 2048);

  swiglu_kernel<<<(M * (ISZ / 8)) / 256, 256, 0, stream>>>(gu);

  gemm_kernel<1><<<dim3(2048 / BN, M / BM), 256, 0, stream>>>(gu, 11264, w2T, w2b, h1, (float*)d_out, M, 2048, 5632);

  (void)in_sizes; (void)n_in; (void)out_size;
}